// Round 1
// baseline (141.641 us; speedup 1.0000x reference)
//
#include <hip/hip_runtime.h>
#include <stdint.h>

#define N_NODES 524288
#define BLOCK 128
#define NUM_BLOCKS 4096
#define MAX_KV 64
#define GRAPH_WEIGHT 0.3f

#define GRID 512
#define THREADS 256
#define NB_PER_WG (NUM_BLOCKS / GRID)        // 8 node-blocks per workgroup
#define ITERS (NB_PER_WG * BLOCK / THREADS)  // 4 iterations of 256 nodes

// ws layout:
//   u32[0] : grid-barrier arrival counter   (memset to 0 each launch)
//   u32[1] : completion counter (last-wg)   (memset to 0 each launch)
// float-indexed from 16:
#define WS_SUMP 16                       // [4096] sum(keep*p) per node-block
#define WS_CNTK (WS_SUMP + NUM_BLOCKS)   // [4096] keep count per node-block
#define WS_BCE  (WS_CNTK + NUM_BLOCKS)   // [512]  per-wg sum(bce*sup)
#define WS_SUP  (WS_BCE + GRID)          // [512]  per-wg sum(sup)
#define WS_GNUM (WS_SUP + GRID)          // [512]  per-wg sum(blk_loss*valid)
#define WS_GCNT (WS_GNUM + GRID)         // [512]  per-wg sum(valid)

__device__ __forceinline__ bool read_mask(const void* p, int i, int bf) {
    if (bf) return ((const uint8_t*)p)[i] != 0;
    return ((const int*)p)[i] != 0;
}

// One fused persistent kernel: phase1 (per-node-block stats) -> grid barrier ->
// phase2 (neighbor means + graph loss) -> last-wg final reduction.
// 512 blocks x 256 threads = 2 wg/CU (8 waves/CU vs 32-wave cap, ~200B LDS):
// co-residency is guaranteed, so the spin barrier cannot deadlock.
__global__ void __launch_bounds__(THREADS, 2)
k_fused(const float* __restrict__ logits, const float* __restrict__ targets,
        const void* __restrict__ sup, const void* __restrict__ ign,
        const int* __restrict__ kvi, const int* __restrict__ kvn,
        float* __restrict__ ws, float* __restrict__ out) {
    const int wg = blockIdx.x, t = threadIdx.x;
    const int lane = t & 63, wave = t >> 6;
    unsigned* cnt = (unsigned*)ws;

    // --- mask-layout detection (byte-packed bool vs int32 0/1) ---
    // 256 threads scan the first 256 words of sup. Byte-packed (p=0.2): some
    // word >1 with P(miss)=0.512^256~3e-75; int32 0/1 can never exceed 1.
    // In-bounds for both layouts (byte: 131072 words, int32: 524288 words).
    __shared__ int sh_flag;
    if (t == 0) sh_flag = 0;
    __syncthreads();
    {
        const unsigned* w = (const unsigned*)sup;
        if (w[t] > 1u) sh_flag = 1;   // benign same-value race
    }
    __syncthreads();
    const int bf = sh_flag;

    __shared__ float sh_red[4][4];
    __shared__ float sh_qcnt[NB_PER_WG];
    __shared__ float sh_nmean[NB_PER_WG];
    __shared__ float sh_ncnt[NB_PER_WG];
    __shared__ int sh_last;

    // per-node state kept in registers across the grid barrier:
    float pj[ITERS];   // sigmoid(x)
    float uj[ITERS];   // 1.0 if uncertain (=~ign & ~sup) else 0.0
    float bce_acc = 0.f, sup_acc = 0.f;

    const int base = wg * (NB_PER_WG * BLOCK);   // 1024 consecutive nodes / wg

    // ---------------- phase 1: per-node-block stats ----------------
    #pragma unroll
    for (int j = 0; j < ITERS; ++j) {
        const int i = base + j * THREADS + t;
        const float x  = logits[i];
        const float tg = targets[i];
        const bool s = read_mask(sup, i, bf);
        const bool g = read_mask(ign, i, bf);
        // stable softplus(x) - t*x
        const float bce = fmaxf(x, 0.f) + log1pf(expf(-fabsf(x))) - tg * x;
        const float p = 1.f / (1.f + expf(-x));
        pj[j] = p;
        const float u = (!g && !s) ? 1.f : 0.f;
        uj[j] = u;
        if (s) { bce_acc += bce; sup_acc += 1.f; }

        float v0 = g ? 0.f : p;     // keep * p
        float v1 = g ? 0.f : 1.f;   // keep count
        float v2 = u;               // uncertain count
        for (int off = 32; off > 0; off >>= 1) {
            v0 += __shfl_down(v0, off);
            v1 += __shfl_down(v1, off);
            v2 += __shfl_down(v2, off);
        }
        if (lane == 0) { sh_red[wave][0] = v0; sh_red[wave][1] = v1; sh_red[wave][2] = v2; }
        __syncthreads();
        if (t < 2) {   // combine wave pairs: waves {0,1}->nb j*2, {2,3}->j*2+1
            const int nbl = j * 2 + t;
            const int nb  = wg * NB_PER_WG + nbl;
            ws[WS_SUMP + nb] = sh_red[2*t][0] + sh_red[2*t+1][0];
            ws[WS_CNTK + nb] = sh_red[2*t][1] + sh_red[2*t+1][1];
            sh_qcnt[nbl]     = sh_red[2*t][2] + sh_red[2*t+1][2];
        }
        __syncthreads();   // protect sh_red before next iteration
    }

    // wg-level reduce of supervised-BCE partials
    for (int off = 32; off > 0; off >>= 1) {
        bce_acc += __shfl_down(bce_acc, off);
        sup_acc += __shfl_down(sup_acc, off);
    }
    if (lane == 0) { sh_red[wave][0] = bce_acc; sh_red[wave][1] = sup_acc; }
    __syncthreads();
    if (t == 0) {
        ws[WS_BCE + wg] = sh_red[0][0] + sh_red[1][0] + sh_red[2][0] + sh_red[3][0];
        ws[WS_SUP + wg] = sh_red[0][1] + sh_red[1][1] + sh_red[2][1] + sh_red[3][1];
    }

    // ---------------- grid barrier (device-scope, spin) ----------------
    __syncthreads();
    if (t == 0) {
        __threadfence();              // release: wb XCD L2 so SUMP/CNTK visible
        atomicAdd(&cnt[0], 1u);
        while (__hip_atomic_load(&cnt[0], __ATOMIC_RELAXED,
                                 __HIP_MEMORY_SCOPE_AGENT) < (unsigned)GRID)
            __builtin_amdgcn_s_sleep(1);
    }
    __syncthreads();
    __threadfence();                  // acquire: invalidate before remote reads

    // ---------------- phase 2: neighbor means ----------------
    // 4 waves handle the wg's 8 node-blocks in 2 rounds (64 lanes = MAX_KV).
    #pragma unroll
    for (int r = 0; r < 2; ++r) {
        const int nbl = r * 4 + wave;
        const int nb  = wg * NB_PER_WG + nbl;
        float ns = 0.f, nc = 0.f;
        const int num = kvn[nb];
        if (lane < num) {
            const int jj = kvi[nb * MAX_KV + lane];
            ns = ws[WS_SUMP + jj];
            nc = ws[WS_CNTK + jj];
        }
        for (int off = 32; off > 0; off >>= 1) {
            ns += __shfl_down(ns, off);
            nc += __shfl_down(nc, off);
        }
        if (lane == 0) { sh_ncnt[nbl] = nc; sh_nmean[nbl] = ns / fmaxf(nc, 1.f); }
    }
    __syncthreads();

    // graph-consistency loss using the register-held p/uncertain
    float gnum_acc = 0.f, gcnt_acc = 0.f;
    #pragma unroll
    for (int j = 0; j < ITERS; ++j) {
        const int nbl = j * 2 + (t >> 7);
        const float d = pj[j] - sh_nmean[nbl];
        float v = uj[j] * d * d;
        for (int off = 32; off > 0; off >>= 1) v += __shfl_down(v, off);
        if (lane == 0) sh_red[wave][0] = v;
        __syncthreads();
        if (t < 2) {
            const int nbl2 = j * 2 + t;
            const float vs = sh_red[2*t][0] + sh_red[2*t+1][0];
            const float qc = sh_qcnt[nbl2];
            const bool valid = (qc > 0.f) && (sh_ncnt[nbl2] > 0.f);
            gnum_acc += valid ? vs / fmaxf(qc, 1.f) : 0.f;
            gcnt_acc += valid ? 1.f : 0.f;
        }
        __syncthreads();
    }
    // partials live in t0,t1 (same wave)
    gnum_acc += __shfl_down(gnum_acc, 1);
    gcnt_acc += __shfl_down(gcnt_acc, 1);
    if (t == 0) { ws[WS_GNUM + wg] = gnum_acc; ws[WS_GCNT + wg] = gcnt_acc; }

    // ---------------- last-wg final reduction ----------------
    __syncthreads();
    if (t == 0) {
        __threadfence();              // release per-wg partials
        const unsigned old = atomicAdd(&cnt[1], 1u);
        sh_last = (old == (unsigned)GRID - 1) ? 1 : 0;
    }
    __syncthreads();
    if (sh_last) {                    // uniform across the block
        __threadfence();              // acquire other wgs' partials
        float b = 0.f, sc = 0.f, gn = 0.f, gc = 0.f;
        for (int w2 = t; w2 < GRID; w2 += THREADS) {
            b  += ws[WS_BCE + w2];
            sc += ws[WS_SUP + w2];
            gn += ws[WS_GNUM + w2];
            gc += ws[WS_GCNT + w2];
        }
        for (int off = 32; off > 0; off >>= 1) {
            b  += __shfl_down(b, off);
            sc += __shfl_down(sc, off);
            gn += __shfl_down(gn, off);
            gc += __shfl_down(gc, off);
        }
        if (lane == 0) {
            sh_red[wave][0] = b; sh_red[wave][1] = sc;
            sh_red[wave][2] = gn; sh_red[wave][3] = gc;
        }
        __syncthreads();
        if (t == 0) {
            const float B  = sh_red[0][0]+sh_red[1][0]+sh_red[2][0]+sh_red[3][0];
            const float S  = sh_red[0][1]+sh_red[1][1]+sh_red[2][1]+sh_red[3][1];
            const float GN = sh_red[0][2]+sh_red[1][2]+sh_red[2][2]+sh_red[3][2];
            const float GC = sh_red[0][3]+sh_red[1][3]+sh_red[2][3]+sh_red[3][3];
            const float loss_sup   = (S > 0.f) ? B / fmaxf(S, 1.f) : 0.f;
            const float loss_graph = GN / fmaxf(GC, 1.f);
            out[0] = loss_sup + GRAPH_WEIGHT * loss_graph;
        }
    }
}

extern "C" void kernel_launch(void* const* d_in, const int* in_sizes, int n_in,
                              void* d_out, int out_size, void* d_ws, size_t ws_size,
                              hipStream_t stream) {
    const float* logits  = (const float*)d_in[0];
    const float* targets = (const float*)d_in[1];
    const void*  sup     = d_in[2];
    const void*  ign     = d_in[3];
    const int*   kvi     = (const int*)d_in[4];
    const int*   kvn     = (const int*)d_in[5];
    float* out = (float*)d_out;
    float* ws  = (float*)d_ws;

    // zero the two barrier counters (graph-capture-safe, 16 bytes)
    hipMemsetAsync(d_ws, 0, 16, stream);
    k_fused<<<GRID, THREADS, 0, stream>>>(logits, targets, sup, ign, kvi, kvn, ws, out);
}

// Round 2
// 82.684 us; speedup vs baseline: 1.7130x; 1.7130x over previous
//
#include <hip/hip_runtime.h>
#include <stdint.h>

#define N_NODES 524288
#define BLOCK 128
#define NUM_BLOCKS 4096
#define MAX_KV 64
#define GRAPH_WEIGHT 0.3f

// ws float-index layout (all per-block partial arrays; no atomics anywhere)
#define WS_SUMP 0            // [4096] sum of keep*p per block
#define WS_CNTK 4096         // [4096] keep count per block
#define WS_QCNT 8192         // [4096] uncertain count per block
#define WS_BCEP 12288        // [4096] per-block sum(bce*sup)
#define WS_SUPP 16384        // [4096] per-block sum(sup)
#define WS_GNUM 20480        // [4096] per-block blk_loss*valid
#define WS_GCNT 24576        // [4096] per-block valid

__device__ __forceinline__ bool read_mask(const void* p, int i, int byteflag) {
    if (byteflag) return ((const uint8_t*)p)[i] != 0;
    return ((const int*)p)[i] != 0;
}

// Block-local mask-layout detection: all blocks scan the same first 256 words
// of sup. Byte-packed bools (p=0.2) give words>1 with P(miss)=0.512^256~=3e-75;
// an int32 0/1 array can never produce a word >1. 256 words are in-bounds for
// both layouts (byte: 131072 words, int32: 524288 words) and L2-broadcast.
__device__ __forceinline__ int detect_byteflag(const void* sup, int t, int* sh_flag) {
    if (t == 0) *sh_flag = 0;
    __syncthreads();
    const unsigned int* w = (const unsigned int*)sup;
    unsigned int a = w[t] | w[t + 128];  // OR>1  <=>  either>1 (values<=1 are {0,1})
    if (a > 1u) *sh_flag = 1;            // benign same-value race
    __syncthreads();
    return *sh_flag;
}

__global__ void __launch_bounds__(BLOCK)
k1_per_block(const float* __restrict__ logits, const float* __restrict__ targets,
             const void* __restrict__ sup, const void* __restrict__ ign,
             float* __restrict__ ws) {
    const int b = blockIdx.x, t = threadIdx.x;
    const int i = b * BLOCK + t;
    __shared__ int sh_flag;
    const int bf = detect_byteflag(sup, t, &sh_flag);
    float x  = logits[i];
    float tg = targets[i];
    bool s = read_mask(sup, i, bf);
    bool g = read_mask(ign, i, bf);
    // stable softplus(x) - t*x
    float bce = fmaxf(x, 0.f) + log1pf(expf(-fabsf(x))) - tg * x;
    float p = 1.f / (1.f + expf(-x));
    float v0 = g ? 0.f : p;              // keep * p
    float v1 = g ? 0.f : 1.f;            // keep count
    float v2 = (!g && !s) ? 1.f : 0.f;   // uncertain count
    float v3 = s ? bce : 0.f;            // sup bce
    float v4 = s ? 1.f : 0.f;            // sup count
    for (int off = 32; off > 0; off >>= 1) {
        v0 += __shfl_down(v0, off);
        v1 += __shfl_down(v1, off);
        v2 += __shfl_down(v2, off);
        v3 += __shfl_down(v3, off);
        v4 += __shfl_down(v4, off);
    }
    __shared__ float sh[2][5];
    if ((t & 63) == 0) {
        int w = t >> 6;
        sh[w][0] = v0; sh[w][1] = v1; sh[w][2] = v2; sh[w][3] = v3; sh[w][4] = v4;
    }
    __syncthreads();
    if (t == 0) {
        ws[WS_SUMP + b] = sh[0][0] + sh[1][0];
        ws[WS_CNTK + b] = sh[0][1] + sh[1][1];
        ws[WS_QCNT + b] = sh[0][2] + sh[1][2];
        ws[WS_BCEP + b] = sh[0][3] + sh[1][3];
        ws[WS_SUPP + b] = sh[0][4] + sh[1][4];
    }
}

__global__ void __launch_bounds__(BLOCK)
k2_graph(const float* __restrict__ logits,
         const void* __restrict__ sup, const void* __restrict__ ign,
         const int* __restrict__ kvi, const int* __restrict__ kvn,
         float* __restrict__ ws) {
    const int b = blockIdx.x, t = threadIdx.x;
    __shared__ int sh_flag;
    const int bf = detect_byteflag(sup, t, &sh_flag);
    __shared__ float sh_nmean, sh_ncnt;
    if (t < 64) {
        float ns = 0.f, nc = 0.f;
        int num = kvn[b];
        if (t < num) {
            int j = kvi[b * MAX_KV + t];
            ns = ws[WS_SUMP + j];
            nc = ws[WS_CNTK + j];
        }
        for (int off = 32; off > 0; off >>= 1) {
            ns += __shfl_down(ns, off);
            nc += __shfl_down(nc, off);
        }
        if (t == 0) {
            sh_ncnt  = nc;
            sh_nmean = ns / fmaxf(nc, 1.f);
        }
    }
    __syncthreads();
    const float nmean = sh_nmean;
    const float ncnt  = sh_ncnt;
    const int i = b * BLOCK + t;
    float x = logits[i];
    bool s = read_mask(sup, i, bf);
    bool g = read_mask(ign, i, bf);
    float p = 1.f / (1.f + expf(-x));
    float d = p - nmean;
    float v = (!g && !s) ? d * d : 0.f;
    for (int off = 32; off > 0; off >>= 1)
        v += __shfl_down(v, off);
    __shared__ float shv[2];
    if ((t & 63) == 0) shv[t >> 6] = v;
    __syncthreads();
    if (t == 0) {
        float vs = shv[0] + shv[1];
        float qc = ws[WS_QCNT + b];
        bool valid = (qc > 0.f) && (ncnt > 0.f);
        ws[WS_GNUM + b] = valid ? vs / fmaxf(qc, 1.f) : 0.f;
        ws[WS_GCNT + b] = valid ? 1.f : 0.f;
    }
}

// Single-block reduction of the 4 per-block partial arrays -> final scalar.
__global__ void __launch_bounds__(256)
k3_final(const float* __restrict__ ws, float* __restrict__ out) {
    const int t = threadIdx.x;
    float bce = 0.f, scnt = 0.f, gnum = 0.f, gcnt = 0.f;
    for (int b = t; b < NUM_BLOCKS; b += 256) {
        bce  += ws[WS_BCEP + b];
        scnt += ws[WS_SUPP + b];
        gnum += ws[WS_GNUM + b];
        gcnt += ws[WS_GCNT + b];
    }
    for (int off = 32; off > 0; off >>= 1) {
        bce  += __shfl_down(bce, off);
        scnt += __shfl_down(scnt, off);
        gnum += __shfl_down(gnum, off);
        gcnt += __shfl_down(gcnt, off);
    }
    __shared__ float sh[4][4];
    if ((t & 63) == 0) {
        int w = t >> 6;
        sh[w][0] = bce; sh[w][1] = scnt; sh[w][2] = gnum; sh[w][3] = gcnt;
    }
    __syncthreads();
    if (t == 0) {
        float bs = sh[0][0] + sh[1][0] + sh[2][0] + sh[3][0];
        float sc = sh[0][1] + sh[1][1] + sh[2][1] + sh[3][1];
        float gn = sh[0][2] + sh[1][2] + sh[2][2] + sh[3][2];
        float gc = sh[0][3] + sh[1][3] + sh[2][3] + sh[3][3];
        float loss_sup = (sc > 0.f) ? bs / fmaxf(sc, 1.f) : 0.f;
        float loss_graph = gn / fmaxf(gc, 1.f);
        out[0] = loss_sup + GRAPH_WEIGHT * loss_graph;
    }
}

extern "C" void kernel_launch(void* const* d_in, const int* in_sizes, int n_in,
                              void* d_out, int out_size, void* d_ws, size_t ws_size,
                              hipStream_t stream) {
    const float* logits  = (const float*)d_in[0];
    const float* targets = (const float*)d_in[1];
    const void*  sup     = d_in[2];
    const void*  ign     = d_in[3];
    const int*   kvi     = (const int*)d_in[4];
    const int*   kvn     = (const int*)d_in[5];
    float* out = (float*)d_out;
    float* ws  = (float*)d_ws;

    k1_per_block<<<NUM_BLOCKS, BLOCK, 0, stream>>>(logits, targets, sup, ign, ws);
    k2_graph<<<NUM_BLOCKS, BLOCK, 0, stream>>>(logits, sup, ign, kvi, kvn, ws);
    k3_final<<<1, 256, 0, stream>>>(ws, out);
}